// Round 1
// baseline (930.879 us; speedup 1.0000x reference)
//
#include <hip/hip_runtime.h>
#include <hip/hip_bf16.h>
#include <cstdint>
#include <cstddef>

typedef unsigned short u16;
typedef __attribute__((ext_vector_type(8))) __bf16 bf16x8;
typedef __attribute__((ext_vector_type(4))) float f32x4;

#define DEV __device__ __forceinline__

// ---------- helpers ----------
DEV u16 f2bf(float f) {
    union { float f; uint32_t u; } c{f};
    uint32_t u = c.u;
    uint32_t r = (u + 0x7fffu + ((u >> 16) & 1u)) >> 16;
    return (u16)r;
}
DEV float bf2f(u16 u) {
    union { uint32_t u; float f; } c{(uint32_t)u << 16};
    return c.f;
}
DEV void gload16(const void* g, void* l) {
    __builtin_amdgcn_global_load_lds((const __attribute__((address_space(1))) void*)g,
                                     (__attribute__((address_space(3))) void*)l, 16, 0, 0);
}

// Problem constants
#define Bb 4
#define Ss 2048
#define KVv 2048
#define Dd 2048
#define Tcat 4096  // KV + S

// ---------- conversion kernels ----------
__global__ __launch_bounds__(256) void k_f32_to_bf16(const float* __restrict__ src,
                                                     u16* __restrict__ dst, int n4) {
    int i = blockIdx.x * 256 + threadIdx.x;
    if (i < n4) {
        float4 v = ((const float4*)src)[i];
        ushort4 o;
        o.x = f2bf(v.x); o.y = f2bf(v.y); o.z = f2bf(v.z); o.w = f2bf(v.w);
        ((ushort4*)dst)[i] = o;
    }
}

// past_k -> cache_k (f32, rows [b*4096 + t], t<2048) + Kcat bf16 same rows
__global__ __launch_bounds__(256) void k_pastk(const float* __restrict__ pk,
                                               float* __restrict__ ck,
                                               u16* __restrict__ kcat) {
    size_t i = (size_t)blockIdx.x * 256 + threadIdx.x; // float4 index, total 4*2048*2048/4
    float4 v = ((const float4*)pk)[i];
    size_t e = i * 4;
    int b = (int)(e >> 22);              // 2048*2048 = 2^22 per batch
    size_t off = e + ((size_t)b << 22);  // -> b*2^23 + within
    *(float4*)(ck + off) = v;
    ushort4 o;
    o.x = f2bf(v.x); o.y = f2bf(v.y); o.z = f2bf(v.z); o.w = f2bf(v.w);
    *(ushort4*)(kcat + off) = o;
}

// past_v -> cache_v (f32 passthrough) + Vt bf16 transposed [b][d][t]
__global__ __launch_bounds__(256) void k_pastv(const float* __restrict__ pv,
                                               float* __restrict__ cv,
                                               u16* __restrict__ vt) {
    __shared__ float tile[32][33];
    int b = blockIdx.z;
    int t0 = blockIdx.x * 32, d0 = blockIdx.y * 32;
    int tx = threadIdx.x & 31, ty = threadIdx.x >> 5; // 32 x 8
#pragma unroll
    for (int i = 0; i < 4; ++i) {
        int t = ty + i * 8;
        float val = pv[((size_t)b * KVv + t0 + t) * Dd + d0 + tx];
        cv[((size_t)b * Tcat + t0 + t) * Dd + d0 + tx] = val;
        tile[t][tx] = val;
    }
    __syncthreads();
#pragma unroll
    for (int i = 0; i < 4; ++i) {
        int d = ty + i * 8;
        vt[((size_t)b * Dd + d0 + d) * Tcat + t0 + tx] = f2bf(tile[tx][d]);
    }
}

// ---------- GEMM: C[m,n] = sum_k A[m,k] * B[n,k]  (both operands [rows][K] bf16) ----------
enum { MQ = 0, MK = 1, MV = 2, MS = 3, MPV = 4 };

template <int MODE>
__global__ __launch_bounds__(256) void gemm_bt(const u16* __restrict__ A,
                                               const u16* __restrict__ Bm, int Kdim,
                                               size_t sAz, size_t sBz,
                                               u16* __restrict__ obf,
                                               float* __restrict__ of32) {
    __shared__ u16 sA[128 * 32]; // 8 KB
    __shared__ u16 sB[128 * 32]; // 8 KB
    const int tid = threadIdx.x;
    const int lane = tid & 63;
    const int w = tid >> 6;
    const int wr = w >> 1, wc = w & 1;
    const int z = blockIdx.z;
    A += (size_t)z * sAz;
    Bm += (size_t)z * sBz;
    const int m0 = blockIdx.y * 128;
    const int n0 = blockIdx.x * 128;

    f32x4 acc[4][4] = {};

    const int r0 = tid >> 2;        // staging row 0..63
    const int kc = (tid & 3) * 8;   // staging k offset (bf16 elems)

    for (int k0 = 0; k0 < Kdim; k0 += 32) {
        __syncthreads();
        {
            const u16* ga = A + (size_t)(m0 + r0) * (size_t)Kdim + (size_t)(k0 + kc);
            gload16(ga, &sA[tid * 8]);
            gload16(ga + (size_t)64 * Kdim, &sA[2048 + tid * 8]);
            const u16* gb = Bm + (size_t)(n0 + r0) * (size_t)Kdim + (size_t)(k0 + kc);
            gload16(gb, &sB[tid * 8]);
            gload16(gb + (size_t)64 * Kdim, &sB[2048 + tid * 8]);
        }
        asm volatile("s_waitcnt vmcnt(0)" ::: "memory");
        __syncthreads();

        const int fr = lane & 15;
        const int kr = (lane >> 4) * 8;
        bf16x8 av[4], bv[4];
#pragma unroll
        for (int mf = 0; mf < 4; ++mf)
            av[mf] = *(const bf16x8*)&sA[(wr * 64 + mf * 16 + fr) * 32 + kr];
#pragma unroll
        for (int nf = 0; nf < 4; ++nf)
            bv[nf] = *(const bf16x8*)&sB[(wc * 64 + nf * 16 + fr) * 32 + kr];
#pragma unroll
        for (int mf = 0; mf < 4; ++mf)
#pragma unroll
            for (int nf = 0; nf < 4; ++nf)
                acc[mf][nf] = __builtin_amdgcn_mfma_f32_16x16x32_bf16(av[mf], bv[nf],
                                                                      acc[mf][nf], 0, 0, 0);
    }

    // epilogue: D layout col=lane&15, row=(lane>>4)*4+r
    const int orow = (lane >> 4) * 4;
    const int ocol = lane & 15;
#pragma unroll
    for (int mf = 0; mf < 4; ++mf) {
#pragma unroll
        for (int nf = 0; nf < 4; ++nf) {
#pragma unroll
            for (int r = 0; r < 4; ++r) {
                int gm = m0 + wr * 64 + mf * 16 + orow + r;
                int gn = n0 + wc * 64 + nf * 16 + ocol;
                float v = acc[mf][nf][r];
                if constexpr (MODE == MQ) {
                    obf[(size_t)gm * Dd + gn] = f2bf(v);
                } else if constexpr (MODE == MK) {
                    size_t crow = (size_t)gm + (size_t)(((unsigned)gm >> 11) + 1) * Ss;
                    obf[crow * Dd + gn] = f2bf(v);
                    of32[crow * Dd + gn] = v;
                } else if constexpr (MODE == MV) {
                    size_t crow = (size_t)gm + (size_t)(((unsigned)gm >> 11) + 1) * Ss;
                    of32[crow * Dd + gn] = v;
                    obf[((size_t)((unsigned)gm >> 11) * Dd + gn) * Tcat + KVv + (gm & 2047)] =
                        f2bf(v);
                } else if constexpr (MODE == MS) {
                    obf[(size_t)z * Ss * Tcat + (size_t)gm * Tcat + gn] = f2bf(v);
                } else { // MPV
                    of32[(size_t)z * Ss * Dd + (size_t)gm * Dd + gn] =
                        rintf(v * 1e4f) * 1e-4f;
                }
            }
        }
    }
}

// ---------- softmax over rows of SP (bf16 in place), row len 4096, scale 1/sqrt(D) ----------
__global__ __launch_bounds__(256) void k_softmax(u16* __restrict__ SP) {
    const size_t row = blockIdx.x;
    u16* p = SP + row * Tcat;
    const int tid = threadIdx.x;
    const int lane = tid & 63;
    const int wv = tid >> 6;
    const float RS = 0.022097086912079608f; // 1/sqrt(2048)

    ushort4 raw[4];
    const ushort4* src = (const ushort4*)(p + tid * 16);
#pragma unroll
    for (int i = 0; i < 4; ++i) raw[i] = src[i];

    float v[16];
#pragma unroll
    for (int i = 0; i < 4; ++i) {
        v[i * 4 + 0] = bf2f(raw[i].x) * RS;
        v[i * 4 + 1] = bf2f(raw[i].y) * RS;
        v[i * 4 + 2] = bf2f(raw[i].z) * RS;
        v[i * 4 + 3] = bf2f(raw[i].w) * RS;
    }
    float mx = v[0];
#pragma unroll
    for (int i = 1; i < 16; ++i) mx = fmaxf(mx, v[i]);
#pragma unroll
    for (int s = 32; s; s >>= 1) mx = fmaxf(mx, __shfl_xor(mx, s));
    __shared__ float redm[4];
    if (lane == 0) redm[wv] = mx;
    __syncthreads();
    mx = fmaxf(fmaxf(redm[0], redm[1]), fmaxf(redm[2], redm[3]));

    float sum = 0.f;
#pragma unroll
    for (int i = 0; i < 16; ++i) {
        v[i] = __expf(v[i] - mx);
        sum += v[i];
    }
#pragma unroll
    for (int s = 32; s; s >>= 1) sum += __shfl_xor(sum, s);
    __shared__ float reds[4];
    if (lane == 0) reds[wv] = sum;
    __syncthreads();
    sum = reds[0] + reds[1] + reds[2] + reds[3];
    float inv = 1.0f / sum;

    ushort4* dst = (ushort4*)(p + tid * 16);
#pragma unroll
    for (int i = 0; i < 4; ++i) {
        ushort4 o;
        o.x = f2bf(v[i * 4 + 0] * inv);
        o.y = f2bf(v[i * 4 + 1] * inv);
        o.z = f2bf(v[i * 4 + 2] * inv);
        o.w = f2bf(v[i * 4 + 3] * inv);
        dst[i] = o;
    }
}

// ---------- launch ----------
extern "C" void kernel_launch(void* const* d_in, const int* in_sizes, int n_in,
                              void* d_out, int out_size, void* d_ws, size_t ws_size,
                              hipStream_t stream) {
    const float* x      = (const float*)d_in[0];
    const float* past_k = (const float*)d_in[1];
    const float* past_v = (const float*)d_in[2];
    const float* Wq     = (const float*)d_in[3];
    const float* Wk     = (const float*)d_in[4];
    const float* Wv     = (const float*)d_in[5];

    float* out     = (float*)d_out;                  // [4,2048,2048]
    float* cache_k = out + (size_t)Bb * Ss * Dd;     // [4,4096,2048]
    float* cache_v = cache_k + (size_t)Bb * Tcat * Dd;

    u16* x_bf  = (u16*)d_ws;                             // 8192*2048
    u16* wq_bf = x_bf + (size_t)Bb * Ss * Dd;            // 2048*2048
    u16* wk_bf = wq_bf + (size_t)Dd * Dd;
    u16* wv_bf = wk_bf + (size_t)Dd * Dd;
    u16* q_bf  = wv_bf + (size_t)Dd * Dd;                // 8192*2048
    u16* kcat  = q_bf + (size_t)Bb * Ss * Dd;            // [4][4096][2048]
    u16* vt    = kcat + (size_t)Bb * Tcat * Dd;          // [4][2048][4096]
    u16* sp    = vt + (size_t)Bb * Dd * Tcat;            // [4][2048][4096]

    // bf16 conversions
    k_f32_to_bf16<<<16384, 256, 0, stream>>>(x, x_bf, (Bb * Ss * Dd) / 4);
    k_f32_to_bf16<<<4096, 256, 0, stream>>>(Wq, wq_bf, (Dd * Dd) / 4);
    k_f32_to_bf16<<<4096, 256, 0, stream>>>(Wk, wk_bf, (Dd * Dd) / 4);
    k_f32_to_bf16<<<4096, 256, 0, stream>>>(Wv, wv_bf, (Dd * Dd) / 4);
    // cache copies (past part)
    k_pastk<<<16384, 256, 0, stream>>>(past_k, cache_k, kcat);
    k_pastv<<<dim3(KVv / 32, Dd / 32, Bb), 256, 0, stream>>>(past_v, cache_v, vt);

    // projections: M=8192, N=2048, K=2048
    gemm_bt<MQ><<<dim3(16, 64, 1), 256, 0, stream>>>(x_bf, wq_bf, Dd, 0, 0, q_bf, nullptr);
    gemm_bt<MK><<<dim3(16, 64, 1), 256, 0, stream>>>(x_bf, wk_bf, Dd, 0, 0, kcat, cache_k);
    gemm_bt<MV><<<dim3(16, 64, 1), 256, 0, stream>>>(x_bf, wv_bf, Dd, 0, 0, vt, cache_v);

    // scores: per b: M=2048, N=4096, K=2048 -> sp
    gemm_bt<MS><<<dim3(32, 16, Bb), 256, 0, stream>>>(q_bf, kcat, Dd,
                                                      (size_t)Ss * Dd, (size_t)Tcat * Dd,
                                                      sp, nullptr);
    // softmax rows
    k_softmax<<<Bb * Ss, 256, 0, stream>>>(sp);

    // PV: per b: M=2048, N=2048, K=4096 -> out (rounded)
    gemm_bt<MPV><<<dim3(16, 16, Bb), 256, 0, stream>>>(sp, vt, Tcat,
                                                       (size_t)Ss * Tcat, (size_t)Dd * Tcat,
                                                       nullptr, out);
}

// Round 2
// 635.143 us; speedup vs baseline: 1.4656x; 1.4656x over previous
//
#include <hip/hip_runtime.h>
#include <hip/hip_bf16.h>
#include <cstdint>
#include <cstddef>

typedef unsigned short u16;
typedef __attribute__((ext_vector_type(8))) __bf16 bf16x8;
typedef __attribute__((ext_vector_type(4))) float f32x4;

#define DEV __device__ __forceinline__

// ---------- helpers ----------
DEV u16 f2bf(float f) {
    union { float f; uint32_t u; } c{f};
    uint32_t u = c.u;
    uint32_t r = (u + 0x7fffu + ((u >> 16) & 1u)) >> 16;
    return (u16)r;
}
DEV float bf2f(u16 u) {
    union { uint32_t u; float f; } c{(uint32_t)u << 16};
    return c.f;
}
DEV void gload16(const void* g, void* l) {
    __builtin_amdgcn_global_load_lds((const __attribute__((address_space(1))) void*)g,
                                     (__attribute__((address_space(3))) void*)l, 16, 0, 0);
}

// Problem constants
#define Bb 4
#define Ss 2048
#define KVv 2048
#define Dd 2048
#define Tcat 4096  // KV + S

// ---------- conversion kernels (unchanged from r1, passed) ----------
__global__ __launch_bounds__(256) void k_f32_to_bf16(const float* __restrict__ src,
                                                     u16* __restrict__ dst, int n4) {
    int i = blockIdx.x * 256 + threadIdx.x;
    if (i < n4) {
        float4 v = ((const float4*)src)[i];
        ushort4 o;
        o.x = f2bf(v.x); o.y = f2bf(v.y); o.z = f2bf(v.z); o.w = f2bf(v.w);
        ((ushort4*)dst)[i] = o;
    }
}

__global__ __launch_bounds__(256) void k_pastk(const float* __restrict__ pk,
                                               float* __restrict__ ck,
                                               u16* __restrict__ kcat) {
    size_t i = (size_t)blockIdx.x * 256 + threadIdx.x;
    float4 v = ((const float4*)pk)[i];
    size_t e = i * 4;
    int b = (int)(e >> 22);
    size_t off = e + ((size_t)b << 22);
    *(float4*)(ck + off) = v;
    ushort4 o;
    o.x = f2bf(v.x); o.y = f2bf(v.y); o.z = f2bf(v.z); o.w = f2bf(v.w);
    *(ushort4*)(kcat + off) = o;
}

__global__ __launch_bounds__(256) void k_pastv(const float* __restrict__ pv,
                                               float* __restrict__ cv,
                                               u16* __restrict__ vt) {
    __shared__ float tile[32][33];
    int b = blockIdx.z;
    int t0 = blockIdx.x * 32, d0 = blockIdx.y * 32;
    int tx = threadIdx.x & 31, ty = threadIdx.x >> 5;
#pragma unroll
    for (int i = 0; i < 4; ++i) {
        int t = ty + i * 8;
        float val = pv[((size_t)b * KVv + t0 + t) * Dd + d0 + tx];
        cv[((size_t)b * Tcat + t0 + t) * Dd + d0 + tx] = val;
        tile[t][tx] = val;
    }
    __syncthreads();
#pragma unroll
    for (int i = 0; i < 4; ++i) {
        int d = ty + i * 8;
        vt[((size_t)b * Dd + d0 + d) * Tcat + t0 + tx] = f2bf(tile[tx][d]);
    }
}

// ---------- 256x256x64 8-phase GEMM: C[m,n] = sum_k A[m,k]*B[n,k] ----------
enum { MQKV = 0, MS = 1, MPV = 2 };

// STAGE one half-tile (128 rows x 64 cols) of A (isA=1) or B into LDS buffer bufi.
// Linear LDS dest (wave-uniform base + lane*16B); global source column pre-swizzled
// by chunk ^= (row&7) so swizzled ds_read sees correct data (rule 21).
#define STAGE(bufi, isA, h, t)                                                        \
    do {                                                                              \
        const u16* gsrc = ((isA) ? A : Bm) +                                          \
                          (size_t)(((isA) ? m0 : n0) + (h) * 128) * (size_t)Kdim +    \
                          (size_t)(t) * 64;                                           \
        u16* ld = &lds[(bufi) * 32768 + ((isA) ? 0 : 16384) + (h) * 8192];            \
        gload16(gsrc + soff0, ld + tid * 8);                                          \
        gload16(gsrc + soff1, ld + 4096 + tid * 8);                                   \
    } while (0)

#define ENDS_BAR __builtin_amdgcn_s_barrier()

#define ENDS_VM(cond)                                                  \
    do {                                                               \
        if (cond) asm volatile("s_waitcnt vmcnt(4)" ::: "memory");     \
        else      asm volatile("s_waitcnt vmcnt(0)" ::: "memory");     \
        __builtin_amdgcn_s_barrier();                                  \
    } while (0)

// One phase: 12 ds_read_b128 -> stage issue -> barrier -> lgkmcnt(0) -> 16 MFMA -> end sync
#define PHASE(bufi, MH, NH, STAGE_STMT, ENDSYNC)                                       \
    do {                                                                               \
        const u16* base_ = &lds[(bufi) * 32768];                                       \
        bf16x8 av[4][2], bv[2][2];                                                     \
        _Pragma("unroll") for (int mfq = 0; mfq < 4; ++mfq) {                          \
            int gmf = ((MH) * 4 + mfq) * 2 + wr;                                       \
            av[mfq][0] = *(const bf16x8*)&base_[gmf * 1024 + rdo0];                    \
            av[mfq][1] = *(const bf16x8*)&base_[gmf * 1024 + rdo1];                    \
        }                                                                              \
        _Pragma("unroll") for (int nfq = 0; nfq < 2; ++nfq) {                          \
            int gnf = ((NH) * 2 + nfq) * 4 + wc;                                       \
            bv[nfq][0] = *(const bf16x8*)&base_[16384 + gnf * 1024 + rdo0];            \
            bv[nfq][1] = *(const bf16x8*)&base_[16384 + gnf * 1024 + rdo1];            \
        }                                                                              \
        STAGE_STMT;                                                                    \
        __builtin_amdgcn_s_barrier();                                                  \
        asm volatile("s_waitcnt lgkmcnt(0)" ::: "memory");                             \
        __builtin_amdgcn_s_setprio(1);                                                 \
        _Pragma("unroll") for (int nfq = 0; nfq < 2; ++nfq)                            \
        _Pragma("unroll") for (int mfq = 0; mfq < 4; ++mfq) {                          \
            acc[(MH) * 4 + mfq][(NH) * 2 + nfq] = __builtin_amdgcn_mfma_f32_16x16x32_bf16( \
                av[mfq][0], bv[nfq][0], acc[(MH) * 4 + mfq][(NH) * 2 + nfq], 0, 0, 0); \
            acc[(MH) * 4 + mfq][(NH) * 2 + nfq] = __builtin_amdgcn_mfma_f32_16x16x32_bf16( \
                av[mfq][1], bv[nfq][1], acc[(MH) * 4 + mfq][(NH) * 2 + nfq], 0, 0, 0); \
        }                                                                              \
        __builtin_amdgcn_s_setprio(0);                                                 \
        ENDSYNC;                                                                       \
    } while (0)

template <int MODE>
__global__ __launch_bounds__(512, 2) void gemm8(const u16* __restrict__ A,
                                                const u16* __restrict__ Bm, int Kdim,
                                                size_t sAz, size_t sBz,
                                                u16* __restrict__ p0, u16* __restrict__ p1,
                                                u16* __restrict__ p2, float* __restrict__ f0,
                                                float* __restrict__ f1) {
    __shared__ u16 lds[65536]; // 128 KiB: [2 bufs][A 16384 | B 16384] u16
    const int tid = threadIdx.x;
    const int lane = tid & 63;
    const int w = tid >> 6;
    const int wr = w >> 2; // 0..1 (M)
    const int wc = w & 3;  // 0..3 (N)

    // bijective XCD swizzle (all grids are multiples of 8 blocks)
    const int gx = gridDim.x, gy = gridDim.y;
    int nwg = gx * gy * gridDim.z;
    int orig = blockIdx.x + gx * (blockIdx.y + gy * blockIdx.z);
    int swz = (orig & 7) * (nwg >> 3) + (orig >> 3);
    int bx = swz % gx;
    int rest = swz / gx;
    int by = rest % gy;
    int bz = rest / gy;

    A += (size_t)bz * sAz;
    Bm += (size_t)bz * sBz;
    const int m0 = by * 256;
    const int n0 = bx * 256;

    // staging per-thread constants (source col pre-swizzled)
    const int c3 = tid & 7;
    const int r0_ = tid >> 3;
    const int r1_ = r0_ + 64;
    const size_t soff0 = (size_t)r0_ * (size_t)Kdim + (size_t)((c3 ^ (r0_ & 7)) * 8);
    const size_t soff1 = (size_t)r1_ * (size_t)Kdim + (size_t)((c3 ^ (r1_ & 7)) * 8);

    // ds_read per-lane swizzled offsets (u16 elems within a matrix region), ks=0/1
    const int l15 = lane & 15;
    const int q = lane >> 4;
    const int s3 = l15 & 7;
    const int rdo0 = l15 * 64 + ((q ^ s3) * 8);
    const int rdo1 = l15 * 64 + (((4 + q) ^ s3) * 8);

    f32x4 acc[8][4] = {};

    const int nt = Kdim >> 6;

    // prologue: tile0 all 4 halves, tile1 A0+B0
    STAGE(0, 1, 0, 0); STAGE(0, 1, 1, 0); STAGE(0, 0, 0, 0); STAGE(0, 0, 1, 0);
    STAGE(1, 1, 0, 1); STAGE(1, 0, 0, 1);
    asm volatile("s_waitcnt vmcnt(4)" ::: "memory");
    __builtin_amdgcn_s_barrier();

    for (int t = 0; t < nt; t += 2) {
        const bool more = (t + 2) < nt;
        const bool more3 = (t + 3) < nt;
        // tile t from buf0
        PHASE(0, 0, 0, STAGE(1, 1, 1, t + 1), ENDS_BAR);              // stage t+1:A1
        PHASE(0, 0, 1, STAGE(1, 0, 1, t + 1), ENDS_BAR);              // stage t+1:B1
        PHASE(0, 1, 0, if (more) STAGE(0, 1, 0, t + 2), ENDS_BAR);    // stage t+2:A0
        PHASE(0, 1, 1, if (more) STAGE(0, 0, 0, t + 2), ENDS_VM(more)); // stage t+2:B0
        // tile t+1 from buf1
        PHASE(1, 0, 0, if (more) STAGE(0, 1, 1, t + 2), ENDS_BAR);    // stage t+2:A1
        PHASE(1, 0, 1, if (more) STAGE(0, 0, 1, t + 2), ENDS_BAR);    // stage t+2:B1
        PHASE(1, 1, 0, if (more3) STAGE(1, 1, 0, t + 3), ENDS_BAR);   // stage t+3:A0
        PHASE(1, 1, 1, if (more3) STAGE(1, 0, 0, t + 3), ENDS_VM(more3)); // t+3:B0
    }

    // epilogue: C/D frag layout col=lane&15, row=(lane>>4)*4+r
    const int orow = (lane >> 4) * 4;
    const int ocol = lane & 15;
#pragma unroll
    for (int mf = 0; mf < 8; ++mf) {
#pragma unroll
        for (int nf = 0; nf < 4; ++nf) {
#pragma unroll
            for (int r = 0; r < 4; ++r) {
                int gm = m0 + (mf * 2 + wr) * 16 + orow + r;
                int gn = n0 + (nf * 4 + wc) * 16 + ocol;
                float v = acc[mf][nf][r];
                if constexpr (MODE == MQKV) {
                    if (gn < 2048) {
                        p0[(size_t)gm * Dd + gn] = f2bf(v); // Q bf16
                    } else {
                        size_t crow = (size_t)gm + (size_t)(((unsigned)gm >> 11) + 1) * Ss;
                        if (gn < 4096) {
                            int nk = gn - 2048;
                            p1[crow * Dd + nk] = f2bf(v); // kcat bf16
                            f0[crow * Dd + nk] = v;       // cache_k f32
                        } else {
                            int nv = gn - 4096;
                            f1[crow * Dd + nv] = v;       // cache_v f32
                            p2[((size_t)((unsigned)gm >> 11) * Dd + nv) * Tcat + KVv +
                               (gm & 2047)] = f2bf(v);    // Vt bf16 transposed
                        }
                    }
                } else if constexpr (MODE == MS) {
                    p0[(size_t)bz * Ss * Tcat + (size_t)gm * Tcat + gn] = f2bf(v);
                } else { // MPV
                    f0[(size_t)bz * Ss * Dd + (size_t)gm * Dd + gn] =
                        rintf(v * 1e4f) * 1e-4f;
                }
            }
        }
    }
}

// ---------- softmax (unchanged from r1, passed) ----------
__global__ __launch_bounds__(256) void k_softmax(u16* __restrict__ SP) {
    const size_t row = blockIdx.x;
    u16* p = SP + row * Tcat;
    const int tid = threadIdx.x;
    const int lane = tid & 63;
    const int wv = tid >> 6;
    const float RS = 0.022097086912079608f; // 1/sqrt(2048)

    ushort4 raw[4];
    const ushort4* src = (const ushort4*)(p + tid * 16);
#pragma unroll
    for (int i = 0; i < 4; ++i) raw[i] = src[i];

    float v[16];
#pragma unroll
    for (int i = 0; i < 4; ++i) {
        v[i * 4 + 0] = bf2f(raw[i].x) * RS;
        v[i * 4 + 1] = bf2f(raw[i].y) * RS;
        v[i * 4 + 2] = bf2f(raw[i].z) * RS;
        v[i * 4 + 3] = bf2f(raw[i].w) * RS;
    }
    float mx = v[0];
#pragma unroll
    for (int i = 1; i < 16; ++i) mx = fmaxf(mx, v[i]);
#pragma unroll
    for (int s = 32; s; s >>= 1) mx = fmaxf(mx, __shfl_xor(mx, s));
    __shared__ float redm[4];
    if (lane == 0) redm[wv] = mx;
    __syncthreads();
    mx = fmaxf(fmaxf(redm[0], redm[1]), fmaxf(redm[2], redm[3]));

    float sum = 0.f;
#pragma unroll
    for (int i = 0; i < 16; ++i) {
        v[i] = __expf(v[i] - mx);
        sum += v[i];
    }
#pragma unroll
    for (int s = 32; s; s >>= 1) sum += __shfl_xor(sum, s);
    __shared__ float reds[4];
    if (lane == 0) reds[wv] = sum;
    __syncthreads();
    sum = reds[0] + reds[1] + reds[2] + reds[3];
    float inv = 1.0f / sum;

    ushort4* dst = (ushort4*)(p + tid * 16);
#pragma unroll
    for (int i = 0; i < 4; ++i) {
        ushort4 o;
        o.x = f2bf(v[i * 4 + 0] * inv);
        o.y = f2bf(v[i * 4 + 1] * inv);
        o.z = f2bf(v[i * 4 + 2] * inv);
        o.w = f2bf(v[i * 4 + 3] * inv);
        dst[i] = o;
    }
}

// ---------- launch ----------
extern "C" void kernel_launch(void* const* d_in, const int* in_sizes, int n_in,
                              void* d_out, int out_size, void* d_ws, size_t ws_size,
                              hipStream_t stream) {
    const float* x      = (const float*)d_in[0];
    const float* past_k = (const float*)d_in[1];
    const float* past_v = (const float*)d_in[2];
    const float* Wq     = (const float*)d_in[3];
    const float* Wk     = (const float*)d_in[4];
    const float* Wv     = (const float*)d_in[5];

    float* out     = (float*)d_out;
    float* cache_k = out + (size_t)Bb * Ss * Dd;
    float* cache_v = cache_k + (size_t)Bb * Tcat * Dd;

    u16* x_bf    = (u16*)d_ws;                            // 8192*2048
    u16* wqkv_bf = x_bf + (size_t)Bb * Ss * Dd;           // 6144*2048 (Wq;Wk;Wv stacked)
    u16* q_bf    = wqkv_bf + (size_t)3 * Dd * Dd;         // 8192*2048
    u16* kcat    = q_bf + (size_t)Bb * Ss * Dd;           // [4][4096][2048]
    u16* vt      = kcat + (size_t)Bb * Tcat * Dd;         // [4][2048][4096]
    u16* sp      = vt + (size_t)Bb * Dd * Tcat;           // [4][2048][4096]

    // bf16 conversions
    k_f32_to_bf16<<<16384, 256, 0, stream>>>(x, x_bf, (Bb * Ss * Dd) / 4);
    k_f32_to_bf16<<<4096, 256, 0, stream>>>(Wq, wqkv_bf, (Dd * Dd) / 4);
    k_f32_to_bf16<<<4096, 256, 0, stream>>>(Wk, wqkv_bf + (size_t)Dd * Dd, (Dd * Dd) / 4);
    k_f32_to_bf16<<<4096, 256, 0, stream>>>(Wv, wqkv_bf + (size_t)2 * Dd * Dd, (Dd * Dd) / 4);
    // cache copies (past part)
    k_pastk<<<16384, 256, 0, stream>>>(past_k, cache_k, kcat);
    k_pastv<<<dim3(KVv / 32, Dd / 32, Bb), 256, 0, stream>>>(past_v, cache_v, vt);

    // fused QKV projection: M=8192, N=6144, K=2048
    gemm8<MQKV><<<dim3(24, 32, 1), 512, 0, stream>>>(x_bf, wqkv_bf, Dd, 0, 0,
                                                     q_bf, kcat, vt, cache_k, cache_v);

    // scores: per b: M=2048, N=4096, K=2048 -> sp
    gemm8<MS><<<dim3(16, 8, Bb), 512, 0, stream>>>(q_bf, kcat, Dd,
                                                   (size_t)Ss * Dd, (size_t)Tcat * Dd,
                                                   sp, nullptr, nullptr, nullptr, nullptr);
    // softmax rows
    k_softmax<<<Bb * Ss, 256, 0, stream>>>(sp);

    // PV: per b: M=2048, N=2048, K=4096 -> out (rounded)
    gemm8<MPV><<<dim3(8, 8, Bb), 512, 0, stream>>>(sp, vt, Tcat,
                                                   (size_t)Ss * Tcat, (size_t)Dd * Tcat,
                                                   nullptr, nullptr, nullptr, out, nullptr);
}

// Round 3
// 628.095 us; speedup vs baseline: 1.4821x; 1.0112x over previous
//
#include <hip/hip_runtime.h>
#include <hip/hip_bf16.h>
#include <cstdint>
#include <cstddef>

typedef unsigned short u16;
typedef __attribute__((ext_vector_type(8))) __bf16 bf16x8;
typedef __attribute__((ext_vector_type(4))) float f32x4;

#define DEV __device__ __forceinline__

// ---------- helpers ----------
DEV u16 f2bf(float f) {
    union { float f; uint32_t u; } c{f};
    uint32_t u = c.u;
    uint32_t r = (u + 0x7fffu + ((u >> 16) & 1u)) >> 16;
    return (u16)r;
}
DEV float bf2f(u16 u) {
    union { uint32_t u; float f; } c{(uint32_t)u << 16};
    return c.f;
}
DEV void gload16(const void* g, void* l) {
    __builtin_amdgcn_global_load_lds((const __attribute__((address_space(1))) void*)g,
                                     (__attribute__((address_space(3))) void*)l, 16, 0, 0);
}

// Problem constants
#define Bb 4
#define Ss 2048
#define KVv 2048
#define Dd 2048
#define Tcat 4096  // KV + S

// ---------- conversion kernels ----------
__global__ __launch_bounds__(256) void k_f32_to_bf16(const float* __restrict__ src,
                                                     u16* __restrict__ dst, int n4) {
    int i = blockIdx.x * 256 + threadIdx.x;
    if (i < n4) {
        float4 v = ((const float4*)src)[i];
        ushort4 o;
        o.x = f2bf(v.x); o.y = f2bf(v.y); o.z = f2bf(v.z); o.w = f2bf(v.w);
        ((ushort4*)dst)[i] = o;
    }
}

__global__ __launch_bounds__(256) void k_pastk(const float* __restrict__ pk,
                                               float* __restrict__ ck,
                                               u16* __restrict__ kcat) {
    size_t i = (size_t)blockIdx.x * 256 + threadIdx.x;
    float4 v = ((const float4*)pk)[i];
    size_t e = i * 4;
    int b = (int)(e >> 22);
    size_t off = e + ((size_t)b << 22);
    *(float4*)(ck + off) = v;
    ushort4 o;
    o.x = f2bf(v.x); o.y = f2bf(v.y); o.z = f2bf(v.z); o.w = f2bf(v.w);
    *(ushort4*)(kcat + off) = o;
}

__global__ __launch_bounds__(256) void k_pastv(const float* __restrict__ pv,
                                               float* __restrict__ cv,
                                               u16* __restrict__ vt) {
    __shared__ float tile[32][33];
    int b = blockIdx.z;
    int t0 = blockIdx.x * 32, d0 = blockIdx.y * 32;
    int tx = threadIdx.x & 31, ty = threadIdx.x >> 5;
#pragma unroll
    for (int i = 0; i < 4; ++i) {
        int t = ty + i * 8;
        float val = pv[((size_t)b * KVv + t0 + t) * Dd + d0 + tx];
        cv[((size_t)b * Tcat + t0 + t) * Dd + d0 + tx] = val;
        tile[t][tx] = val;
    }
    __syncthreads();
#pragma unroll
    for (int i = 0; i < 4; ++i) {
        int d = ty + i * 8;
        vt[((size_t)b * Dd + d0 + d) * Tcat + t0 + tx] = f2bf(tile[tx][d]);
    }
}

// transpose new V rows: cache_v[b][KVv+t][d] (f32) -> vt[b][d][KVv+t] (bf16)
__global__ __launch_bounds__(256) void k_vtnew(const float* __restrict__ cv,
                                               u16* __restrict__ vt) {
    __shared__ float tile[32][33];
    int b = blockIdx.z;
    int t0 = blockIdx.x * 32 + KVv;
    int d0 = blockIdx.y * 32;
    int tx = threadIdx.x & 31, ty = threadIdx.x >> 5;
#pragma unroll
    for (int i = 0; i < 4; ++i) {
        int t = ty + i * 8;
        tile[t][tx] = cv[((size_t)b * Tcat + t0 + t) * Dd + d0 + tx];
    }
    __syncthreads();
#pragma unroll
    for (int i = 0; i < 4; ++i) {
        int d = ty + i * 8;
        vt[((size_t)b * Dd + d0 + d) * Tcat + t0 + tx] = f2bf(tile[tx][d]);
    }
}

// ---------- 256x256x64 8-phase GEMM: C[m,n] = sum_k A[m,k]*B[n,k] ----------
enum { MQKV = 0, MS = 1, MPV = 2 };

#define STAGE(bufi, isA, h, t)                                                        \
    do {                                                                              \
        const u16* gsrc = ((isA) ? A : Bm) +                                          \
                          (size_t)(((isA) ? m0 : n0) + (h) * 128) * (size_t)Kdim +    \
                          (size_t)(t) * 64;                                           \
        u16* ld = &lds[(bufi) * 32768 + ((isA) ? 0 : 16384) + (h) * 8192];            \
        gload16(gsrc + soff0, ld + tid * 8);                                          \
        gload16(gsrc + soff1, ld + 4096 + tid * 8);                                   \
    } while (0)

#define ENDS_BAR __builtin_amdgcn_s_barrier()

#define ENDS_VM(cond)                                                  \
    do {                                                               \
        if (cond) asm volatile("s_waitcnt vmcnt(4)" ::: "memory");     \
        else      asm volatile("s_waitcnt vmcnt(0)" ::: "memory");     \
        __builtin_amdgcn_s_barrier();                                  \
    } while (0)

#define PHASE(bufi, MH, NH, STAGE_STMT, ENDSYNC)                                       \
    do {                                                                               \
        const u16* base_ = &lds[(bufi) * 32768];                                       \
        bf16x8 av[4][2], bv[2][2];                                                     \
        _Pragma("unroll") for (int mfq = 0; mfq < 4; ++mfq) {                          \
            int gmf = ((MH) * 4 + mfq) * 2 + wr;                                       \
            av[mfq][0] = *(const bf16x8*)&base_[gmf * 1024 + rdo0];                    \
            av[mfq][1] = *(const bf16x8*)&base_[gmf * 1024 + rdo1];                    \
        }                                                                              \
        _Pragma("unroll") for (int nfq = 0; nfq < 2; ++nfq) {                          \
            int gnf = ((NH) * 2 + nfq) * 4 + wc;                                       \
            bv[nfq][0] = *(const bf16x8*)&base_[16384 + gnf * 1024 + rdo0];            \
            bv[nfq][1] = *(const bf16x8*)&base_[16384 + gnf * 1024 + rdo1];            \
        }                                                                              \
        STAGE_STMT;                                                                    \
        __builtin_amdgcn_s_barrier();                                                  \
        asm volatile("s_waitcnt lgkmcnt(0)" ::: "memory");                             \
        __builtin_amdgcn_s_setprio(1);                                                 \
        _Pragma("unroll") for (int nfq = 0; nfq < 2; ++nfq)                            \
        _Pragma("unroll") for (int mfq = 0; mfq < 4; ++mfq) {                          \
            acc[(MH) * 4 + mfq][(NH) * 2 + nfq] = __builtin_amdgcn_mfma_f32_16x16x32_bf16( \
                av[mfq][0], bv[nfq][0], acc[(MH) * 4 + mfq][(NH) * 2 + nfq], 0, 0, 0); \
            acc[(MH) * 4 + mfq][(NH) * 2 + nfq] = __builtin_amdgcn_mfma_f32_16x16x32_bf16( \
                av[mfq][1], bv[nfq][1], acc[(MH) * 4 + mfq][(NH) * 2 + nfq], 0, 0, 0); \
        }                                                                              \
        __builtin_amdgcn_s_setprio(0);                                                 \
        ENDSYNC;                                                                       \
    } while (0)

template <int MODE>
__global__ __launch_bounds__(512, 2) void gemm8(const u16* __restrict__ A,
                                                const u16* __restrict__ Bm, int Kdim,
                                                size_t sAz, size_t sBz,
                                                u16* __restrict__ p0, u16* __restrict__ p1,
                                                float* __restrict__ f0,
                                                float* __restrict__ f1) {
    __shared__ u16 lds[65536]; // 128 KiB
    const int tid = threadIdx.x;
    const int lane = tid & 63;
    const int w = tid >> 6;
    const int wr = w >> 2; // 0..1 (M)
    const int wc = w & 3;  // 0..3 (N)

    const int gx = gridDim.x, gy = gridDim.y;
    int nwg = gx * gy * gridDim.z;
    int orig = blockIdx.x + gx * (blockIdx.y + gy * blockIdx.z);
    int swz = (orig & 7) * (nwg >> 3) + (orig >> 3);
    int bx = swz % gx;
    int rest = swz / gx;
    int by = rest % gy;
    int bz = rest / gy;

    A += (size_t)bz * sAz;
    Bm += (size_t)bz * sBz;
    const int m0 = by * 256;
    const int n0 = bx * 256;

    const int c3 = tid & 7;
    const int r0_ = tid >> 3;
    const int r1_ = r0_ + 64;
    const size_t soff0 = (size_t)r0_ * (size_t)Kdim + (size_t)((c3 ^ (r0_ & 7)) * 8);
    const size_t soff1 = (size_t)r1_ * (size_t)Kdim + (size_t)((c3 ^ (r1_ & 7)) * 8);

    const int l15 = lane & 15;
    const int q = lane >> 4;
    const int s3 = l15 & 7;
    const int rdo0 = l15 * 64 + ((q ^ s3) * 8);
    const int rdo1 = l15 * 64 + (((4 + q) ^ s3) * 8);

    f32x4 acc[8][4] = {};

    const int nt = Kdim >> 6;

    STAGE(0, 1, 0, 0); STAGE(0, 1, 1, 0); STAGE(0, 0, 0, 0); STAGE(0, 0, 1, 0);
    STAGE(1, 1, 0, 1); STAGE(1, 0, 0, 1);
    asm volatile("s_waitcnt vmcnt(4)" ::: "memory");
    __builtin_amdgcn_s_barrier();

    for (int t = 0; t < nt; t += 2) {
        const bool more = (t + 2) < nt;
        const bool more3 = (t + 3) < nt;
        PHASE(0, 0, 0, STAGE(1, 1, 1, t + 1), ENDS_BAR);
        PHASE(0, 0, 1, STAGE(1, 0, 1, t + 1), ENDS_BAR);
        PHASE(0, 1, 0, if (more) STAGE(0, 1, 0, t + 2), ENDS_BAR);
        PHASE(0, 1, 1, if (more) STAGE(0, 0, 0, t + 2), ENDS_VM(more));
        PHASE(1, 0, 0, if (more) STAGE(0, 1, 1, t + 2), ENDS_BAR);
        PHASE(1, 0, 1, if (more) STAGE(0, 0, 1, t + 2), ENDS_BAR);
        PHASE(1, 1, 0, if (more3) STAGE(1, 1, 0, t + 3), ENDS_BAR);
        PHASE(1, 1, 1, if (more3) STAGE(1, 0, 0, t + 3), ENDS_VM(more3));
    }

    // epilogue: C/D frag layout col=lane&15, row=(lane>>4)*4+r
    const int orow = (lane >> 4) * 4;
    const int ocol = lane & 15;
#pragma unroll
    for (int mf = 0; mf < 8; ++mf) {
#pragma unroll
        for (int nf = 0; nf < 4; ++nf) {
#pragma unroll
            for (int r = 0; r < 4; ++r) {
                int gm = m0 + (mf * 2 + wr) * 16 + orow + r;
                int gn = n0 + (nf * 4 + wc) * 16 + ocol;
                float v = acc[mf][nf][r];
                if constexpr (MODE == MQKV) {
                    if (gn < 2048) {
                        p0[(size_t)gm * Dd + gn] = f2bf(v); // Q bf16
                    } else {
                        size_t crow = (size_t)gm + (size_t)(((unsigned)gm >> 11) + 1) * Ss;
                        if (gn < 4096) {
                            int nk = gn - 2048;
                            p1[crow * Dd + nk] = f2bf(v); // kcat bf16
                            f0[crow * Dd + nk] = v;       // cache_k f32
                        } else {
                            int nv = gn - 4096;
                            f1[crow * Dd + nv] = v;       // cache_v f32 (vt done later)
                        }
                    }
                } else if constexpr (MODE == MS) {
                    p0[(size_t)bz * Ss * Tcat + (size_t)gm * Tcat + gn] = f2bf(v);
                } else { // MPV
                    f0[(size_t)bz * Ss * Dd + (size_t)gm * Dd + gn] =
                        rintf(v * 1e4f) * 1e-4f;
                }
            }
        }
    }
}

// ---------- softmax ----------
__global__ __launch_bounds__(256) void k_softmax(u16* __restrict__ SP) {
    const size_t row = blockIdx.x;
    u16* p = SP + row * Tcat;
    const int tid = threadIdx.x;
    const int lane = tid & 63;
    const int wv = tid >> 6;
    const float RS = 0.022097086912079608f; // 1/sqrt(2048)

    ushort4 raw[4];
    const ushort4* src = (const ushort4*)(p + tid * 16);
#pragma unroll
    for (int i = 0; i < 4; ++i) raw[i] = src[i];

    float v[16];
#pragma unroll
    for (int i = 0; i < 4; ++i) {
        v[i * 4 + 0] = bf2f(raw[i].x) * RS;
        v[i * 4 + 1] = bf2f(raw[i].y) * RS;
        v[i * 4 + 2] = bf2f(raw[i].z) * RS;
        v[i * 4 + 3] = bf2f(raw[i].w) * RS;
    }
    float mx = v[0];
#pragma unroll
    for (int i = 1; i < 16; ++i) mx = fmaxf(mx, v[i]);
#pragma unroll
    for (int s = 32; s; s >>= 1) mx = fmaxf(mx, __shfl_xor(mx, s));
    __shared__ float redm[4];
    if (lane == 0) redm[wv] = mx;
    __syncthreads();
    mx = fmaxf(fmaxf(redm[0], redm[1]), fmaxf(redm[2], redm[3]));

    float sum = 0.f;
#pragma unroll
    for (int i = 0; i < 16; ++i) {
        v[i] = __expf(v[i] - mx);
        sum += v[i];
    }
#pragma unroll
    for (int s = 32; s; s >>= 1) sum += __shfl_xor(sum, s);
    __shared__ float reds[4];
    if (lane == 0) reds[wv] = sum;
    __syncthreads();
    sum = reds[0] + reds[1] + reds[2] + reds[3];
    float inv = 1.0f / sum;

    ushort4* dst = (ushort4*)(p + tid * 16);
#pragma unroll
    for (int i = 0; i < 4; ++i) {
        ushort4 o;
        o.x = f2bf(v[i * 4 + 0] * inv);
        o.y = f2bf(v[i * 4 + 1] * inv);
        o.z = f2bf(v[i * 4 + 2] * inv);
        o.w = f2bf(v[i * 4 + 3] * inv);
        dst[i] = o;
    }
}

// ---------- launch ----------
extern "C" void kernel_launch(void* const* d_in, const int* in_sizes, int n_in,
                              void* d_out, int out_size, void* d_ws, size_t ws_size,
                              hipStream_t stream) {
    const float* x      = (const float*)d_in[0];
    const float* past_k = (const float*)d_in[1];
    const float* past_v = (const float*)d_in[2];
    const float* Wq     = (const float*)d_in[3];
    const float* Wk     = (const float*)d_in[4];
    const float* Wv     = (const float*)d_in[5];

    float* out     = (float*)d_out;
    float* cache_k = out + (size_t)Bb * Ss * Dd;
    float* cache_v = cache_k + (size_t)Bb * Tcat * Dd;

    u16* x_bf    = (u16*)d_ws;
    u16* wqkv_bf = x_bf + (size_t)Bb * Ss * Dd;
    u16* q_bf    = wqkv_bf + (size_t)3 * Dd * Dd;
    u16* kcat    = q_bf + (size_t)Bb * Ss * Dd;
    u16* vt      = kcat + (size_t)Bb * Tcat * Dd;
    u16* sp      = vt + (size_t)Bb * Dd * Tcat;

    // bf16 conversions
    k_f32_to_bf16<<<16384, 256, 0, stream>>>(x, x_bf, (Bb * Ss * Dd) / 4);
    k_f32_to_bf16<<<4096, 256, 0, stream>>>(Wq, wqkv_bf, (Dd * Dd) / 4);
    k_f32_to_bf16<<<4096, 256, 0, stream>>>(Wk, wqkv_bf + (size_t)Dd * Dd, (Dd * Dd) / 4);
    k_f32_to_bf16<<<4096, 256, 0, stream>>>(Wv, wqkv_bf + (size_t)2 * Dd * Dd, (Dd * Dd) / 4);
    // cache copies (past part)
    k_pastk<<<16384, 256, 0, stream>>>(past_k, cache_k, kcat);
    k_pastv<<<dim3(KVv / 32, Dd / 32, Bb), 256, 0, stream>>>(past_v, cache_v, vt);

    // fused QKV projection: M=8192, N=6144, K=2048
    gemm8<MQKV><<<dim3(24, 32, 1), 512, 0, stream>>>(x_bf, wqkv_bf, Dd, 0, 0,
                                                     q_bf, kcat, cache_k, cache_v);

    // transpose new V rows into vt
    k_vtnew<<<dim3(Ss / 32, Dd / 32, Bb), 256, 0, stream>>>(cache_v, vt);

    // scores: per b: M=2048, N=4096, K=2048 -> sp
    gemm8<MS><<<dim3(16, 8, Bb), 512, 0, stream>>>(q_bf, kcat, Dd,
                                                   (size_t)Ss * Dd, (size_t)Tcat * Dd,
                                                   sp, nullptr, nullptr, nullptr);
    // softmax rows
    k_softmax<<<Bb * Ss, 256, 0, stream>>>(sp);

    // PV: per b: M=2048, N=2048, K=4096 -> out (rounded)
    gemm8<MPV><<<dim3(8, 8, Bb), 512, 0, stream>>>(sp, vt, Tcat,
                                                   (size_t)Ss * Tcat, (size_t)Dd * Tcat,
                                                   nullptr, nullptr, out, nullptr);
}